// Round 2
// baseline (3356.000 us; speedup 1.0000x reference)
//
#include <hip/hip_runtime.h>

#define DEV __device__ __forceinline__

using short8 = __attribute__((ext_vector_type(8))) short;
using f32x4  = __attribute__((ext_vector_type(4))) float;

DEV float b2f(short s) {
  union { unsigned u; float f; } c;
  c.u = ((unsigned)(unsigned short)s) << 16;
  return c.f;
}
DEV short f2b(float f) {
  union { float f; unsigned u; } c; c.f = f;
  unsigned u = c.u + 0x7fffu + ((c.u >> 16) & 1u);
  return (short)(u >> 16);
}
// async global->LDS, 16B per lane. LDS dest = uniform base + lane*16.
DEV void async_ld16(const void* g, void* lds) {
  __builtin_amdgcn_global_load_lds(
      (const __attribute__((address_space(1))) void*)(unsigned long long)g,
      (__attribute__((address_space(3))) void*)(unsigned)(unsigned long long)lds,
      16, 0, 0);
}

// ---------------- init: flags + hx[0] ----------------
__global__ void k_init(int* flags, short* hx) {
  int i = blockIdx.x * 256 + threadIdx.x;
  if (i < 1026) flags[i] = (i == 0 || i == 513) ? 8 : 0;
  if (i < 8192) { hx[i] = 0; hx[4202496 + i] = 0; }
}

// ---------------- fp32 -> bf16 convert ----------------
__global__ __launch_bounds__(256) void k_cvt(const float* __restrict__ in,
                                             short* __restrict__ out, int n4) {
  int i = blockIdx.x * 256 + threadIdx.x;
  if (i < n4) {
    f32x4 v = *(const f32x4*)(in + i * 4);
    short4 o;
#pragma unroll
    for (int j = 0; j < 4; j++) ((short*)&o)[j] = f2b(v[j]);
    *(short4*)(out + i * 4) = o;
  }
}

// ---------------- fp32 (R,C) -> bf16 (C,R) transpose+convert ----------------
__global__ __launch_bounds__(256) void k_transcvt(const float* __restrict__ in,
                                                  short* __restrict__ out, int R, int C) {
  __shared__ float tile[32][33];
  int ct = (C + 31) >> 5;
  int bc = blockIdx.x % ct, br = blockIdx.x / ct;
  int r0 = br << 5, c0 = bc << 5;
  for (int i = threadIdx.x; i < 1024; i += 256) {
    int r = i >> 5, c = i & 31;
    int gr = r0 + r, gc = c0 + c;
    tile[r][c] = (gr < R && gc < C) ? in[(size_t)gr * C + gc] : 0.f;
  }
  __syncthreads();
  for (int i = threadIdx.x; i < 1024; i += 256) {
    int c = i >> 5, r = i & 31;
    int gr = r0 + r, gc = c0 + c;
    if (gr < R && gc < C) out[(size_t)gc * R + gr] = f2b(tile[r][c]);
  }
}

// ---------------- embed + positional encoding (fp32 W -> bf16 h0) ----------------
__global__ __launch_bounds__(256) void k_embed(const int* __restrict__ x,
                                               const float* __restrict__ W,
                                               short* __restrict__ h0) {
  int flat = blockIdx.x * 256 + threadIdx.x;   // 0 .. 1048575 (B*T*E/8)
  int row  = flat >> 6;                        // b*T + t
  int e0   = (flat & 63) << 3;
  int tok  = x[row];
  int t    = row & 511;
  const float* wp = W + (size_t)tok * 512 + e0;
  float v[8];
  *(f32x4*)v       = *(const f32x4*)(wp);
  *(f32x4*)(v + 4) = *(const f32x4*)(wp + 4);
  short8 o;
#pragma unroll
  for (int i = 0; i < 8; i += 2) {
    float f = expf(-9.210340371976184f * (float)(e0 + i) * (1.f / 512.f));
    float ang = (float)t * f;
    o[i]     = f2b(v[i]     + sinf(ang));
    o[i + 1] = f2b(v[i + 1] + cosf(ang));
  }
  *(short8*)(h0 + (size_t)flat * 8) = o;
}

// ---------------- 128x128 MFMA GEMM, A(M,K) bf16 * B(N,K) bf16 ----------------
// LDS tiles in MFMA fragment order: chunk c = kb*8 + mb holds a 16x32 block as
// 64 lanes x 16B -> ds_read_b128 at lane*16 conflict-free.
// MODE 0: fp32 out + fp32 bias.  MODE 1: bf16 out + fp32 bias + relu.
template <int MODE>
__global__ __launch_bounds__(256) void k_gemm(const short* __restrict__ A,
    const short* __restrict__ B, const float* __restrict__ bias,
    float* __restrict__ Cf, short* __restrict__ Cb, int M, int N, int K) {
  __shared__ short smA[8192];
  __shared__ short smB[8192];
  const int tid = threadIdx.x, lane = tid & 63, wave = tid >> 6;
  const int m15 = lane & 15, q8 = (lane >> 4) << 3;
  const int tn = N >> 7;
  const int bm = blockIdx.x / tn, bn = blockIdx.x % tn;
  const int wm = wave & 1, wn = wave >> 1;
  const f32x4 z4 = {0.f, 0.f, 0.f, 0.f};
  f32x4 acc[4][4];
#pragma unroll
  for (int i = 0; i < 4; i++)
#pragma unroll
    for (int j = 0; j < 4; j++) acc[i][j] = z4;

  for (int k0 = 0; k0 < K; k0 += 64) {
#pragma unroll
    for (int is = 0; is < 4; is++) {
      int c = is * 4 + wave;
      int mb = c & 7, kb = c >> 3;
      async_ld16(A + (size_t)(bm * 128 + mb * 16 + m15) * K + k0 + kb * 32 + q8, smA + c * 512);
      async_ld16(B + (size_t)(bn * 128 + mb * 16 + m15) * K + k0 + kb * 32 + q8, smB + c * 512);
    }
    __syncthreads();
#pragma unroll
    for (int kk = 0; kk < 2; kk++) {
      short8 af[4], bf[4];
#pragma unroll
      for (int i = 0; i < 4; i++)
        af[i] = *(const short8*)(smA + (kk * 8 + wm * 4 + i) * 512 + lane * 8);
#pragma unroll
      for (int j = 0; j < 4; j++)
        bf[j] = *(const short8*)(smB + (kk * 8 + wn * 4 + j) * 512 + lane * 8);
#pragma unroll
      for (int i = 0; i < 4; i++)
#pragma unroll
        for (int j = 0; j < 4; j++)
          acc[i][j] = __builtin_amdgcn_mfma_f32_16x16x32_bf16(af[i], bf[j], acc[i][j], 0, 0, 0);
    }
    __syncthreads();
  }
#pragma unroll
  for (int j = 0; j < 4; j++) {
    int col = bn * 128 + wn * 64 + j * 16 + m15;
    float bv = bias[col];
#pragma unroll
    for (int i = 0; i < 4; i++) {
      int row0 = bm * 128 + wm * 64 + i * 16 + ((lane >> 4) << 2);
#pragma unroll
      for (int r = 0; r < 4; r++) {
        float v = acc[i][j][r] + bv;
        size_t off = (size_t)(row0 + r) * N + col;
        if (MODE == 0) Cf[off] = v;
        else { if (v < 0.f) v = 0.f; Cb[off] = f2b(v); }
      }
    }
  }
}

// ---------------- bidirectional GRU recurrence ----------------
// 16 blocks: dir = blk>>3, w = blk&7. Block owns h cols [32w,32w+32) ->
// gate rows {g, 256+g, 512+g}. w_hh slice (bf16) LDS-resident in frag order.
// h exchanged per step through hx[s] (bf16) + per-step flag counters.
__global__ __launch_bounds__(256) void k_gru(
    const short* __restrict__ whh_f, const short* __restrict__ whh_b,
    const float* __restrict__ bhh_f, const float* __restrict__ bhh_b,
    const float* __restrict__ gi_f, const float* __restrict__ gi_b,
    short* __restrict__ hx, int* __restrict__ flags,
    short* __restrict__ hcat16, float* __restrict__ hres) {
  __shared__ short smW[24576];      // 48 chunks * 512 shorts
  __shared__ float smG[3200];       // gh: 32 rows x stride 100
  const int blk = blockIdx.x;
  const int d = blk >> 3, w = blk & 7;
  const int tid = threadIdx.x, lane = tid & 63, wave = tid >> 6;
  const int m15 = lane & 15, q8 = (lane >> 4) << 3;
  const short* whh = d ? whh_b : whh_f;
  const float* bhh = d ? bhh_b : bhh_f;
  const float* gi  = d ? gi_b : gi_f;
  short* myhx = hx + (size_t)d * 4202496;
  int* F = flags + d * 513;

  for (int c = wave; c < 48; c += 4) {
    int nb = c >> 3, kb = c & 7;
    int grow = (nb >> 1) * 256 + w * 32 + ((nb & 1) << 4) + m15;
    async_ld16(whh + (size_t)grow * 256 + kb * 32 + q8, smW + c * 512);
  }
  const int cb = tid >> 3, cj = (tid & 7) << 2;
  float bh_r[4], bh_z[4], bh_n[4], hprev[4];
#pragma unroll
  for (int i = 0; i < 4; i++) {
    int g = w * 32 + cj + i;
    bh_r[i] = bhh[g]; bh_z[i] = bhh[256 + g]; bh_n[i] = bhh[512 + g];
    hprev[i] = 0.f;
  }
  const int mt = wave >> 1, ntb = (wave & 1) * 3;
  const f32x4 z4 = {0.f, 0.f, 0.f, 0.f};
  __syncthreads();   // drains whh staging too

  for (int s = 0; s < 512; s++) {
    int t = d ? (511 - s) : s;
    if (tid == 0)
      while (__hip_atomic_load(F + s, __ATOMIC_ACQUIRE, __HIP_MEMORY_SCOPE_AGENT) < 8) {}
    __syncthreads();
    const short* hxs = myhx + (size_t)s * 8192;
    short8 afr[8];
#pragma unroll
    for (int kb = 0; kb < 8; kb++)
      afr[kb] = *(const short8*)(hxs + (mt * 16 + m15) * 256 + kb * 32 + q8);
    f32x4 acc[3]; acc[0] = z4; acc[1] = z4; acc[2] = z4;
#pragma unroll
    for (int kb = 0; kb < 8; kb++) {
#pragma unroll
      for (int j = 0; j < 3; j++) {
        short8 bfr = *(const short8*)(smW + ((ntb + j) * 8 + kb) * 512 + lane * 8);
        acc[j] = __builtin_amdgcn_mfma_f32_16x16x32_bf16(afr[kb], bfr, acc[j], 0, 0, 0);
      }
    }
#pragma unroll
    for (int j = 0; j < 3; j++) {
      int col = (ntb + j) * 16 + m15;
#pragma unroll
      for (int r = 0; r < 4; r++)
        smG[(mt * 16 + (lane >> 4) * 4 + r) * 100 + col] = acc[j][r];
    }
    __syncthreads();
    const float* gip = gi + ((size_t)(cb * 512 + t)) * 768 + w * 32 + cj;
    f32x4 ir  = *(const f32x4*)(gip);
    f32x4 iz  = *(const f32x4*)(gip + 256);
    f32x4 in_ = *(const f32x4*)(gip + 512);
    f32x4 gr = *(const f32x4*)(smG + cb * 100 + cj);
    f32x4 gz = *(const f32x4*)(smG + cb * 100 + 32 + cj);
    f32x4 gn = *(const f32x4*)(smG + cb * 100 + 64 + cj);
    short4 hb4; f32x4 hf4;
#pragma unroll
    for (int i = 0; i < 4; i++) {
      float r = 1.f / (1.f + expf(-(ir[i] + gr[i] + bh_r[i])));
      float z = 1.f / (1.f + expf(-(iz[i] + gz[i] + bh_z[i])));
      float n = tanhf(in_[i] + r * (gn[i] + bh_n[i]));
      float h = (1.f - z) * n + z * hprev[i];
      hprev[i] = h; hf4[i] = h;
      ((short*)&hb4)[i] = f2b(h);
    }
    *(short4*)(myhx + (size_t)(s + 1) * 8192 + cb * 256 + w * 32 + cj) = hb4;
    size_t orow = ((size_t)(cb * 512 + t)) * 512 + d * 256 + w * 32 + cj;
    *(short4*)(hcat16 + orow) = hb4;
    *(f32x4*)(hres + orow) = hf4;
    __syncthreads();   // stores drained (vmcnt) before flag release
    if (tid == 0)
      __hip_atomic_fetch_add(F + s + 1, 1, __ATOMIC_RELEASE, __HIP_MEMORY_SCOPE_AGENT);
  }
}

// ---------------- residual + LayerNorm (fp32 g/b) ----------------
__global__ __launch_bounds__(256) void k_ln(const float* __restrict__ hin,
    const float* __restrict__ ff, const float* __restrict__ gw,
    const float* __restrict__ bw, float* __restrict__ hout, short* __restrict__ h16) {
  int row = blockIdx.x * 4 + (threadIdx.x >> 6);
  int lane = threadIdx.x & 63;
  size_t base = (size_t)row * 512 + lane * 8;
  f32x4 x0 = *(const f32x4*)(hin + base);
  f32x4 x1 = *(const f32x4*)(hin + base + 4);
  f32x4 y0 = *(const f32x4*)(ff + base);
  f32x4 y1 = *(const f32x4*)(ff + base + 4);
  x0 += y0; x1 += y1;
  float s = x0[0] + x0[1] + x0[2] + x0[3] + x1[0] + x1[1] + x1[2] + x1[3];
#pragma unroll
  for (int off = 32; off >= 1; off >>= 1) s += __shfl_xor(s, off);
  float mu = s * (1.f / 512.f);
  float v = 0.f;
#pragma unroll
  for (int i = 0; i < 4; i++) { float d0 = x0[i] - mu, d1 = x1[i] - mu; v += d0 * d0 + d1 * d1; }
#pragma unroll
  for (int off = 32; off >= 1; off >>= 1) v += __shfl_xor(v, off);
  float rs = rsqrtf(v * (1.f / 512.f) + 1e-5f);
  int e = lane * 8;
  f32x4 g0 = *(const f32x4*)(gw + e), g1 = *(const f32x4*)(gw + e + 4);
  f32x4 bb0 = *(const f32x4*)(bw + e), bb1 = *(const f32x4*)(bw + e + 4);
  f32x4 o0, o1; short8 ob;
#pragma unroll
  for (int i = 0; i < 4; i++) {
    float a = (x0[i] - mu) * rs * g0[i] + bb0[i];
    float b = (x1[i] - mu) * rs * g1[i] + bb1[i];
    o0[i] = a; o1[i] = b; ob[i] = f2b(a); ob[4 + i] = f2b(b);
  }
  *(f32x4*)(hout + base) = o0;
  *(f32x4*)(hout + base + 4) = o1;
  *(short8*)(h16 + base) = ob;
}

// ---------------- final FC (N=16), fp32 weights read directly ----------------
__global__ __launch_bounds__(256) void k_fc(const float* __restrict__ h,
    const float* __restrict__ fcw, const float* __restrict__ bias,
    float* __restrict__ logits) {
  int row = blockIdx.x * 4 + (threadIdx.x >> 6);
  int lane = threadIdx.x & 63;
  int c = lane & 15, part = lane >> 4;
  const float* ph = h + (size_t)row * 512 + part * 128;
  const float* pw = fcw + (size_t)part * 128 * 16 + c;    // fcw is (512,16)
  float acc = 0.f;
#pragma unroll 8
  for (int k = 0; k < 128; k += 4) {
    f32x4 hv = *(const f32x4*)(ph + k);
    acc += hv[0] * pw[(k) * 16] + hv[1] * pw[(k + 1) * 16]
         + hv[2] * pw[(k + 2) * 16] + hv[3] * pw[(k + 3) * 16];
  }
  acc += __shfl_xor(acc, 16);
  acc += __shfl_xor(acc, 32);
  if (part == 0) logits[(size_t)row * 16 + c] = acc + bias[c];
}

// ---------------- CRF Viterbi: 1 wave per batch element (fp32 out) ----------------
__global__ __launch_bounds__(64) void k_crf(const float* __restrict__ logits,
    const int* __restrict__ y, const float* __restrict__ trans,
    float* __restrict__ out) {
  __shared__ float tr[16][16];
  __shared__ unsigned char bp[511][16];
  int b = blockIdx.x, lane = threadIdx.x;
  for (int i = lane; i < 256; i += 64) tr[i >> 4][i & 15] = trans[i];
  __syncthreads();
  int cur = lane & 15;
  const float* lg = logits + (size_t)b * 8192;
  const int* yb = y + b * 512;
  float score = tr[1][cur] + lg[cur];          // trans[BOS=1] + emit[0]
  float e_next = lg[16 + cur];
  int y_next = yb[1];
  for (int t = 1; t < 512; t++) {
    float e = e_next; int ym = y_next;
    if (t < 511) { e_next = lg[(t + 1) * 16 + cur]; y_next = yb[t + 1]; }
    float best = -3.4e38f; int arg = 0;
#pragma unroll
    for (int p = 0; p < 16; p++) {
      float cand = __shfl(score, p) + tr[p][cur];
      if (cand > best) { best = cand; arg = p; }   // strict > : first-index argmax
    }
    if (lane < 16) bp[t - 1][cur] = (unsigned char)arg;
    float ns = best + e;
    if (ym == 0) ns = score;                        // mask (y is never PAD here)
    score = ns;
  }
  score += tr[cur][2];                              // + trans[:, EOS=2]
  float best = -3.4e38f; int argb = 0;
#pragma unroll
  for (int p = 0; p < 16; p++) {
    float sp = __shfl(score, p);
    if (sp > best) { best = sp; argb = p; }
  }
  __syncthreads();
  if (lane == 0) {
    out[b] = best;
    float* po = out + 32 + (size_t)b * 512;
    int tag = argb;
    po[511] = (float)tag;
    for (int t = 511; t >= 1; t--) {
      int prev = bp[t - 1][tag];
      if (yb[t] == 0) prev = tag;
      po[t - 1] = (float)prev;
      tag = prev;
    }
  }
}

// ---------------- host ----------------
extern "C" void kernel_launch(void* const* d_in, const int* in_sizes, int n_in,
                              void* d_out, int out_size, void* d_ws, size_t ws_size,
                              hipStream_t stream) {
  const int*   x      = (const int*)d_in[0];
  const int*   y      = (const int*)d_in[1];
  const float* embedW = (const float*)d_in[2];
  const float* w_ih_f = (const float*)d_in[3];
  const float* w_hh_f = (const float*)d_in[4];
  const float* b_ih_f = (const float*)d_in[5];
  const float* b_hh_f = (const float*)d_in[6];
  const float* w_ih_b = (const float*)d_in[7];
  const float* w_hh_b = (const float*)d_in[8];
  const float* b_ih_b = (const float*)d_in[9];
  const float* b_hh_b = (const float*)d_in[10];
  const float* ff_w1  = (const float*)d_in[11];
  const float* ff_b1  = (const float*)d_in[12];
  const float* ff_w2  = (const float*)d_in[13];
  const float* ff_b2  = (const float*)d_in[14];
  const float* ln_g   = (const float*)d_in[15];
  const float* ln_b   = (const float*)d_in[16];
  const float* fc_w   = (const float*)d_in[17];
  const float* fc_b   = (const float*)d_in[18];
  const float* trans  = (const float*)d_in[19];
  float* out = (float*)d_out;

  char* ws = (char*)d_ws;
  // layout (bytes); total ~204.8 MB
  short* h0     = (short*)(ws + 0);                       // 16.78 MB bf16 (B,T,E)
  float* gi_f   = (float*)(ws + 16777216);                // 50.33 MB fp32
  float* gi_b   = (float*)(ws + 67108864);                // 50.33 MB fp32
  short* mid    = (short*)(ws + 16777216);                // overlays gi (dead after GRU)
  float* ffout  = (float*)(ws + 83886080);                // 33.55 MB fp32 (overlays gi_b tail)
  short* wihf16 = (short*)(ws + 117440512);               // 0.79 MB bf16 (768,512)
  short* wihb16 = (short*)(ws + 118226944);               // 0.79 MB
  short* whhf16 = (short*)(ws + 119013376);               // 0.39 MB bf16 (768,256)
  short* whhb16 = (short*)(ws + 119406592);               // 0.39 MB
  short* w1t    = (short*)(ws + 119799808);               // 8.39 MB bf16 (4 x 2048x512)
  short* w2t    = (short*)(ws + 128188416);               // 8.39 MB bf16 (4 x 512x2048)
  short* hx     = (short*)(ws + 136577024);               // 16.81 MB (2 x 513 x 32 x 256)
  int*   flags  = (int*)  (ws + 153387008);               // 2 x 513 ints (+pad)
  short* hcat16 = (short*)(ws + 153395200);               // 16.78 MB bf16 (B,T,512)
  float* hres   = (float*)(ws + 170172416);               // 33.55 MB fp32 residual
  float* logits = (float*)(ws + 203726848);               // 1.05 MB fp32

  k_init<<<32, 256, 0, stream>>>(flags, hx);
  k_embed<<<4096, 256, 0, stream>>>(x, embedW, h0);
  k_cvt<<<384, 256, 0, stream>>>(w_ih_f, wihf16, 98304);
  k_cvt<<<384, 256, 0, stream>>>(w_ih_b, wihb16, 98304);
  k_cvt<<<192, 256, 0, stream>>>(w_hh_f, whhf16, 49152);
  k_cvt<<<192, 256, 0, stream>>>(w_hh_b, whhb16, 49152);
  for (int i = 0; i < 4; i++)
    k_transcvt<<<1024, 256, 0, stream>>>(ff_w1 + (size_t)i * 1048576, w1t + (size_t)i * 1048576, 512, 2048);
  for (int i = 0; i < 4; i++)
    k_transcvt<<<1024, 256, 0, stream>>>(ff_w2 + (size_t)i * 1048576, w2t + (size_t)i * 1048576, 2048, 512);

  k_gemm<0><<<768, 256, 0, stream>>>(h0, wihf16, b_ih_f, gi_f, nullptr, 16384, 768, 512);
  k_gemm<0><<<768, 256, 0, stream>>>(h0, wihb16, b_ih_b, gi_b, nullptr, 16384, 768, 512);

  k_gru<<<16, 256, 0, stream>>>(whhf16, whhb16, b_hh_f, b_hh_b, gi_f, gi_b, hx, flags, hcat16, hres);

  for (int i = 0; i < 4; i++) {
    k_gemm<1><<<2048, 256, 0, stream>>>(hcat16, w1t + (size_t)i * 1048576, ff_b1 + i * 2048,
                                        nullptr, mid, 16384, 2048, 512);
    k_gemm<0><<<512, 256, 0, stream>>>(mid, w2t + (size_t)i * 1048576, ff_b2 + i * 512,
                                       ffout, nullptr, 16384, 512, 2048);
    k_ln<<<4096, 256, 0, stream>>>(hres, ffout, ln_g + i * 512, ln_b + i * 512, hres, hcat16);
  }
  k_fc<<<4096, 256, 0, stream>>>(hres, fc_w, fc_b, logits);
  k_crf<<<32, 64, 0, stream>>>(logits, y, trans, out);
}